// Round 13
// baseline (208.030 us; speedup 1.0000x reference)
//
#include <hip/hip_runtime.h>

// VSGNet fused pipeline — fp32 in/out, bf16 MFMA compute.
// B=64 P=16 L=16 D=1024 SP=32 PROJ=512 ACT=29, C=16384.
// R12 post-mortem: split-K atomics regressed (write traffic x1.8). R13: kill the
// big prep stage (R7 evidence: it never paid for itself). GEMMs read raw fp32
// activations/weights: A via float4-pairs, B via 8 strided dwords, with
// convert-at-consumption double-buffering (raw regs in the rotate so the
// waitcnt lands on old loads, not the just-issued prefetch). Only tiny head
// transposes (~163K elems) remain as prep. ws back to 2.97 MB.

typedef unsigned short u16;   // bf16 bits
typedef short s16x8 __attribute__((ext_vector_type(8)));
typedef float f32x4 __attribute__((ext_vector_type(4)));

__device__ __forceinline__ u16 f2b(float f) {
    union { float f; unsigned int i; } v; v.f = f;
    unsigned int r = (v.i + 0x7fffu + ((v.i >> 16) & 1u)) >> 16;  // RNE
    return (u16)r;
}
__device__ __forceinline__ float b2f(u16 u) {
    union { float f; unsigned int i; } v; v.i = ((unsigned int)u) << 16; return v.f;
}
__device__ __forceinline__ unsigned int pack2(float x, float y) {
    return (unsigned int)f2b(x) | ((unsigned int)f2b(y) << 16);
}

// raw 8-float contiguous fragment (2x float4) — convert at use
struct f8 { float4 lo, hi; };
__device__ __forceinline__ f8 ldr8(const float* p) {
    f8 r; r.lo = *(const float4*)p; r.hi = *(const float4*)(p + 4); return r;
}
__device__ __forceinline__ s16x8 cvt8(const f8& x) {
    s16x8 r;
    r[0] = (short)f2b(x.lo.x); r[1] = (short)f2b(x.lo.y);
    r[2] = (short)f2b(x.lo.z); r[3] = (short)f2b(x.lo.w);
    r[4] = (short)f2b(x.hi.x); r[5] = (short)f2b(x.hi.y);
    r[6] = (short)f2b(x.hi.z); r[7] = (short)f2b(x.hi.w);
    return r;
}
// raw strided fragment: 8 dwords at stride ld (row-major W, k-dim strided)
struct fs8 { float v[8]; };
__device__ __forceinline__ fs8 ldbr(const float* p, int ld) {
    fs8 r;
#pragma unroll
    for (int j = 0; j < 8; j++) r.v[j] = p[(size_t)j * ld];
    return r;
}
__device__ __forceinline__ s16x8 cvts(const fs8& x) {
    s16x8 r;
#pragma unroll
    for (int j = 0; j < 8; j++) r[j] = (short)f2b(x.v[j]);
    return r;
}

#define MFMA(a, b, c) __builtin_amdgcn_mfma_f32_16x16x32_bf16((a), (b), (c), 0, 0, 0)

// ---------------- workspace layout (bytes), total 2,973,696 ----------------
#define OFF_WSPATT 0u         // [512][32]  bf16
#define OFF_WREFT  32768u     // [32][512]  bf16 (rows 29..31 zero)
#define OFF_WATTT  65536u     // [32][512]  bf16
#define OFF_WGT    98304u     // [32][2048] bf16
#define OFF_PP     229376u    // [1024][512] bf16
#define OFF_PO     1277952u   // [1024][512] bf16
#define OFF_PC     2326528u   // [64][512]  bf16
#define OFF_ADJ    2392064u   // [16384] f32
#define OFF_HP     2457600u   // [1024][32] f32
#define OFF_HOF    2588672u   // [1024][32] f32
#define OFF_YH     2719744u   // [1024][32] f32
#define OFF_ZO     2850816u   // [960][32]  f32
#define ZERO_OFF   2457600u
#define ZERO_LEN   516096u

// ---------------- tiny head transposes only ----------------
__global__ __launch_bounds__(256) void prep_heads(
    const float* __restrict__ Wspat, const float* __restrict__ Wref,
    const float* __restrict__ Watt, const float* __restrict__ Wg,
    u16* __restrict__ WspatT, u16* __restrict__ WrefT,
    u16* __restrict__ WattT, u16* __restrict__ WgT)
{
    int g = blockIdx.x * 256 + threadIdx.x;
    int gsz = gridDim.x * 256;
    for (int i = g; i < 512 * 32; i += gsz) {          // WspatT[n][k]
        int n = i >> 5, k = i & 31;
        WspatT[i] = f2b(Wspat[k * 512 + n]);
    }
    for (int i = g; i < 32 * 512; i += gsz) {          // WrefT/WattT [n][k]
        int n = i >> 9, k = i & 511;
        WrefT[i] = (n < 29) ? f2b(Wref[k * 29 + n]) : (u16)0;
        WattT[i] = (n < 29) ? f2b(Watt[k * 29 + n]) : (u16)0;
    }
    for (int i = g; i < 32 * 2048; i += gsz) {         // WgT[n][k]
        int n = i >> 11, k = i & 2047;
        WgT[i] = (n < 29) ? f2b(Wg[k * 29 + n]) : (u16)0;
    }
}

// ---------------- fused GEMMs, raw fp32 operands (904 blocks) ---------------
// [0,264):   Pp/Po/Pc = {people,objects,context} @ Wvis slices (64x64, K=1024)
// [264,776): Yh/Zo relu-projection (block 64x64, 2x2 waves; z=0:256, z=1:256)
// [776,904): Hp/HoF split-K (8x8x2)
__global__ __launch_bounds__(256) void fused_gemms(
    const float* __restrict__ people, const float* __restrict__ objects,
    const float* __restrict__ context, const float* __restrict__ Wvis,
    const float* __restrict__ Who, const float* __restrict__ Who_b,
    const float* __restrict__ Woh, const float* __restrict__ Woh_b,
    const u16* __restrict__ WgT,
    u16* __restrict__ Pp, u16* __restrict__ Po, u16* __restrict__ Pc,
    float* __restrict__ Yh, float* __restrict__ Zo,
    float* __restrict__ Hp, float* __restrict__ HoF)
{
    __shared__ u16 T[64][72];
    int bid = blockIdx.x;
    int t = threadIdx.x;
    int lane = t & 63, w = t >> 6;
    int l16 = lane & 15, q = lane >> 4;
    int wy = w >> 1, wx = w & 1;

    if (bid < 264) {
        // -------- gemm3: A fp32 contiguous, B fp32 strided --------
        int bx = bid & 7, ty = bid >> 3;
        const float* A; u16* outB; const float* W; int bm;
        if (ty < 16)      { A = people;  outB = Pp; W = Wvis;                      bm = ty * 64; }
        else if (ty < 32) { A = objects; outB = Po; W = Wvis + (size_t)1024 * 512; bm = (ty - 16) * 64; }
        else              { A = context; outB = Pc; W = Wvis + (size_t)2048 * 512; bm = 0; }
        int bn = bx * 64;

        const float* ap0 = A + (size_t)(bm + wy * 32 + l16) * 1024 + q * 8;
        const float* ap1 = ap0 + (size_t)16 * 1024;
        const float* wp0 = W + (size_t)(q * 8) * 512 + bn + wx * 32 + l16;
        const float* wp1 = wp0 + 16;

        f32x4 acc00 = {0,0,0,0}, acc01 = {0,0,0,0}, acc10 = {0,0,0,0}, acc11 = {0,0,0,0};
        f8 ca0 = ldr8(ap0), ca1 = ldr8(ap1);
        fs8 cb0 = ldbr(wp0, 512), cb1 = ldbr(wp1, 512);
        ap0 += 32; ap1 += 32; wp0 += (size_t)32 * 512; wp1 += (size_t)32 * 512;
        f8 na0 = ldr8(ap0), na1 = ldr8(ap1);
        fs8 nb0 = ldbr(wp0, 512), nb1 = ldbr(wp1, 512);
        ap0 += 32; ap1 += 32; wp0 += (size_t)32 * 512; wp1 += (size_t)32 * 512;
        for (int it = 0; it < 30; it += 2) {
            s16x8 A0 = cvt8(ca0), A1 = cvt8(ca1), B0 = cvts(cb0), B1 = cvts(cb1);
            ca0 = ldr8(ap0); ca1 = ldr8(ap1);
            cb0 = ldbr(wp0, 512); cb1 = ldbr(wp1, 512);
            ap0 += 32; ap1 += 32; wp0 += (size_t)32 * 512; wp1 += (size_t)32 * 512;
            acc00 = MFMA(A0, B0, acc00); acc01 = MFMA(A0, B1, acc01);
            acc10 = MFMA(A1, B0, acc10); acc11 = MFMA(A1, B1, acc11);
            A0 = cvt8(na0); A1 = cvt8(na1); B0 = cvts(nb0); B1 = cvts(nb1);
            na0 = ldr8(ap0); na1 = ldr8(ap1);
            nb0 = ldbr(wp0, 512); nb1 = ldbr(wp1, 512);
            ap0 += 32; ap1 += 32; wp0 += (size_t)32 * 512; wp1 += (size_t)32 * 512;
            acc00 = MFMA(A0, B0, acc00); acc01 = MFMA(A0, B1, acc01);
            acc10 = MFMA(A1, B0, acc10); acc11 = MFMA(A1, B1, acc11);
        }
        {   // tail: iters 30, 31
            s16x8 A0 = cvt8(ca0), A1 = cvt8(ca1), B0 = cvts(cb0), B1 = cvts(cb1);
            acc00 = MFMA(A0, B0, acc00); acc01 = MFMA(A0, B1, acc01);
            acc10 = MFMA(A1, B0, acc10); acc11 = MFMA(A1, B1, acc11);
            A0 = cvt8(na0); A1 = cvt8(na1); B0 = cvts(nb0); B1 = cvts(nb1);
            acc00 = MFMA(A0, B0, acc00); acc01 = MFMA(A0, B1, acc01);
            acc10 = MFMA(A1, B0, acc10); acc11 = MFMA(A1, B1, acc11);
        }
        f32x4 accs[2][2] = {{acc00, acc01}, {acc10, acc11}};
#pragma unroll
        for (int ii = 0; ii < 2; ii++)
#pragma unroll
            for (int jj = 0; jj < 2; jj++) {
                int col = bn + wx * 32 + jj * 16 + l16;
#pragma unroll
                for (int r = 0; r < 4; r++) {
                    int row = bm + wy * 32 + ii * 16 + q * 4 + r;
                    outB[(size_t)row * 512 + col] = f2b(accs[ii][jj][r]);
                }
            }
    } else if (bid < 776) {
        // -------- relu-projection: block 64x64, waves 2x2 (32x32) --------
        int r3 = bid - 264;
        int z = r3 >> 8; r3 &= 255;
        int rt = r3 >> 4, nbt = r3 & 15;
        const float* A  = z ? objects : people;
        const float* W1 = z ? Woh : Who;
        const float* bb = z ? Woh_b : Who_b;
        const u16* Wg2  = z ? WgT : WgT + 1024;
        float* U        = z ? Zo : Yh;
        int m0 = rt * 64, nb = nbt * 64;

        int r0 = m0 + wy * 32 + l16;
        int r1 = r0 + 16;
        if (z) {
            int rc0 = r0 < 960 ? r0 : 959, rc1 = r1 < 960 ? r1 : 959;
            r0 = (rc0 / 15) * 16 + (rc0 % 15) + 1;
            r1 = (rc1 / 15) * 16 + (rc1 % 15) + 1;
        }
        const float* ap0 = A + (size_t)r0 * 1024 + q * 8;
        const float* ap1 = A + (size_t)r1 * 1024 + q * 8;
        const float* wp0 = W1 + (size_t)(q * 8) * 1024 + nb + wx * 32 + l16;
        const float* wp1 = wp0 + 16;

        f32x4 acc00 = {0,0,0,0}, acc01 = {0,0,0,0}, acc10 = {0,0,0,0}, acc11 = {0,0,0,0};
        f8 ca0 = ldr8(ap0), ca1 = ldr8(ap1);
        fs8 cb0 = ldbr(wp0, 1024), cb1 = ldbr(wp1, 1024);
        ap0 += 32; ap1 += 32; wp0 += (size_t)32 * 1024; wp1 += (size_t)32 * 1024;
        f8 na0 = ldr8(ap0), na1 = ldr8(ap1);
        fs8 nb0 = ldbr(wp0, 1024), nb1 = ldbr(wp1, 1024);
        ap0 += 32; ap1 += 32; wp0 += (size_t)32 * 1024; wp1 += (size_t)32 * 1024;
        for (int it = 0; it < 30; it += 2) {
            s16x8 A0 = cvt8(ca0), A1 = cvt8(ca1), B0 = cvts(cb0), B1 = cvts(cb1);
            ca0 = ldr8(ap0); ca1 = ldr8(ap1);
            cb0 = ldbr(wp0, 1024); cb1 = ldbr(wp1, 1024);
            ap0 += 32; ap1 += 32; wp0 += (size_t)32 * 1024; wp1 += (size_t)32 * 1024;
            acc00 = MFMA(A0, B0, acc00); acc01 = MFMA(A0, B1, acc01);
            acc10 = MFMA(A1, B0, acc10); acc11 = MFMA(A1, B1, acc11);
            A0 = cvt8(na0); A1 = cvt8(na1); B0 = cvts(nb0); B1 = cvts(nb1);
            na0 = ldr8(ap0); na1 = ldr8(ap1);
            nb0 = ldbr(wp0, 1024); nb1 = ldbr(wp1, 1024);
            ap0 += 32; ap1 += 32; wp0 += (size_t)32 * 1024; wp1 += (size_t)32 * 1024;
            acc00 = MFMA(A0, B0, acc00); acc01 = MFMA(A0, B1, acc01);
            acc10 = MFMA(A1, B0, acc10); acc11 = MFMA(A1, B1, acc11);
        }
        {
            s16x8 A0 = cvt8(ca0), A1 = cvt8(ca1), B0 = cvts(cb0), B1 = cvts(cb1);
            acc00 = MFMA(A0, B0, acc00); acc01 = MFMA(A0, B1, acc01);
            acc10 = MFMA(A1, B0, acc10); acc11 = MFMA(A1, B1, acc11);
            A0 = cvt8(na0); A1 = cvt8(na1); B0 = cvts(nb0); B1 = cvts(nb1);
            acc00 = MFMA(A0, B0, acc00); acc01 = MFMA(A0, B1, acc01);
            acc10 = MFMA(A1, B0, acc10); acc11 = MFMA(A1, B1, acc11);
        }

        // bias + relu -> T[64][72] (cols partitioned across nb-blocks)
        f32x4 accs[2][2] = {{acc00, acc01}, {acc10, acc11}};
#pragma unroll
        for (int ii = 0; ii < 2; ii++)
#pragma unroll
            for (int jj = 0; jj < 2; jj++) {
                int col = wx * 32 + jj * 16 + l16;
                float bv = bb[nb + col];
#pragma unroll
                for (int rr = 0; rr < 4; rr++) {
                    float v = accs[ii][jj][rr] + bv;
                    T[wy * 32 + ii * 16 + q * 4 + rr][col] = f2b(fmaxf(v, 0.f));
                }
            }
        __syncthreads();

        // stage 2: U_part[64x32] = T(64x64) @ Wg2[nb:nb+64, :32]; wave 16 rows
        f32x4 s20 = {0,0,0,0}, s21 = {0,0,0,0};
#pragma unroll
        for (int kk = 0; kk < 64; kk += 32) {
            s16x8 a2 = *(const s16x8*)(&T[w * 16 + l16][kk + q * 8]);
            s16x8 b20 = *(const s16x8*)(Wg2 + (size_t)l16 * 2048 + nb + kk + q * 8);
            s16x8 b21 = *(const s16x8*)(Wg2 + (size_t)(16 + l16) * 2048 + nb + kk + q * 8);
            s20 = MFMA(a2, b20, s20);
            s21 = MFMA(a2, b21, s21);
        }
#pragma unroll
        for (int rr = 0; rr < 4; rr++) {
            int row = m0 + w * 16 + q * 4 + rr;
            if (!z || row < 960) {
                atomicAdd(&U[(size_t)row * 32 + l16], s20[rr]);
                atomicAdd(&U[(size_t)row * 32 + 16 + l16], s21[rr]);
            }
        }
    } else {
        // -------- bt32 split-K: 128 rows, 128-k chunk; A fp32, B bf16 --------
        int r3 = bid - 776;
        int bx = r3 & 7, by = (r3 >> 3) & 7, z = r3 >> 6;
        const float* A = z ? objects : people;
        const u16* BT  = z ? WgT + 1024 : WgT;
        float* outF    = z ? HoF : Hp;
        int bm = bx * 128 + w * 32;
        int kb = by * 128;
        const float* ap0 = A + (size_t)(bm + l16) * 1024 + kb + q * 8;
        const float* ap1 = A + (size_t)(bm + 16 + l16) * 1024 + kb + q * 8;
        const u16* bp0 = BT + (size_t)l16 * 2048 + kb + q * 8;
        const u16* bp1 = BT + (size_t)(16 + l16) * 2048 + kb + q * 8;
        f32x4 acc00 = {0,0,0,0}, acc01 = {0,0,0,0}, acc10 = {0,0,0,0}, acc11 = {0,0,0,0};
        f8 ca0 = ldr8(ap0), ca1 = ldr8(ap1);
        s16x8 cb0 = *(const s16x8*)bp0, cb1 = *(const s16x8*)bp1;
        ap0 += 32; ap1 += 32; bp0 += 32; bp1 += 32;
        f8 na0 = ldr8(ap0), na1 = ldr8(ap1);
        s16x8 nb0 = *(const s16x8*)bp0, nb1 = *(const s16x8*)bp1;
        ap0 += 32; ap1 += 32; bp0 += 32; bp1 += 32;
        {   // iter 0, prefetch iter 2
            s16x8 A0 = cvt8(ca0), A1 = cvt8(ca1);
            ca0 = ldr8(ap0); ca1 = ldr8(ap1);
            s16x8 tb0 = *(const s16x8*)bp0, tb1 = *(const s16x8*)bp1;
            ap0 += 32; ap1 += 32; bp0 += 32; bp1 += 32;
            acc00 = MFMA(A0, cb0, acc00); acc01 = MFMA(A0, cb1, acc01);
            acc10 = MFMA(A1, cb0, acc10); acc11 = MFMA(A1, cb1, acc11);
            cb0 = tb0; cb1 = tb1;
        }
        {   // iter 1, prefetch iter 3
            s16x8 A0 = cvt8(na0), A1 = cvt8(na1);
            na0 = ldr8(ap0); na1 = ldr8(ap1);
            s16x8 tb0 = *(const s16x8*)bp0, tb1 = *(const s16x8*)bp1;
            acc00 = MFMA(A0, nb0, acc00); acc01 = MFMA(A0, nb1, acc01);
            acc10 = MFMA(A1, nb0, acc10); acc11 = MFMA(A1, nb1, acc11);
            nb0 = tb0; nb1 = tb1;
        }
        {   // iters 2, 3
            s16x8 A0 = cvt8(ca0), A1 = cvt8(ca1);
            acc00 = MFMA(A0, cb0, acc00); acc01 = MFMA(A0, cb1, acc01);
            acc10 = MFMA(A1, cb0, acc10); acc11 = MFMA(A1, cb1, acc11);
            A0 = cvt8(na0); A1 = cvt8(na1);
            acc00 = MFMA(A0, nb0, acc00); acc01 = MFMA(A0, nb1, acc01);
            acc10 = MFMA(A1, nb0, acc10); acc11 = MFMA(A1, nb1, acc11);
        }
        f32x4 accs[2][2] = {{acc00, acc01}, {acc10, acc11}};
#pragma unroll
        for (int ii = 0; ii < 2; ii++)
#pragma unroll
            for (int jj = 0; jj < 2; jj++)
#pragma unroll
                for (int r = 0; r < 4; r++)
                    atomicAdd(&outF[(size_t)(bm + ii * 16 + q * 4 + r) * 32 + jj * 16 + l16],
                              accs[ii][jj][r]);
    }
}

// ---- mega: per 32-row tile: aho(MFMA) -> p_att -> fref(in-place LDS)+i_ho -> p_ref
// tile [32][520]: row stride 1040B = 4 banks mod 32 (conflict-free).
__global__ __launch_bounds__(256) void mega(
    const float* __restrict__ spatial, const u16* __restrict__ WspatT,
    const float* __restrict__ bspat,
    const u16* __restrict__ Pp, const u16* __restrict__ Po,
    const u16* __restrict__ Pc, const float* __restrict__ bvis,
    const u16* __restrict__ WrefT, const float* __restrict__ bref,
    const u16* __restrict__ WattT, const float* __restrict__ batt,
    const float* __restrict__ wip, const float* __restrict__ bip,
    float* __restrict__ outI, float* __restrict__ outRef,
    float* __restrict__ outAtt, float* __restrict__ adjw)
{
    __shared__ u16 tile[32][520];
    __shared__ float part[32][8];
    __shared__ float wipS[512];
    int t = threadIdx.x;
    int c0 = blockIdx.x * 32;
    int lane = t & 63, w = t >> 6;
    int l16 = lane & 15, q = lane >> 4;

    {
        float2 u = *(const float2*)(wip + t * 2);
        wipS[t * 2]     = u.x;
        wipS[t * 2 + 1] = u.y;
    }

    // step 1: aho rows c0..c0+31; wave w owns cols [w*128, w*128+128)
    {
        f8 ra0 = ldr8(spatial + (size_t)(c0 + l16) * 32 + q * 8);
        f8 ra1 = ldr8(spatial + (size_t)(c0 + 16 + l16) * 32 + q * 8);
        s16x8 a0 = cvt8(ra0), a1 = cvt8(ra1);
        const u16* wb = WspatT + (size_t)(w * 128 + l16) * 32 + q * 8;
        s16x8 cb = *(const s16x8*)wb;
        s16x8 nb_ = *(const s16x8*)(wb + 16 * 32);
        wb += 32 * 32;
#pragma unroll
        for (int nt = 0; nt < 8; nt++) {
            s16x8 tb = nb_;
            if (nt < 6) { tb = *(const s16x8*)wb; wb += 16 * 32; }
            int n = w * 128 + nt * 16;
            f32x4 acc0 = {0,0,0,0}, acc1 = {0,0,0,0};
            acc0 = MFMA(a0, cb, acc0);
            acc1 = MFMA(a1, cb, acc1);
            cb = nb_; nb_ = tb;
            float bias = bspat[n + l16];
#pragma unroll
            for (int r = 0; r < 4; r++) {
                tile[q * 4 + r][n + l16]      = f2b(fmaxf(acc0[r] + bias, 0.f));
                tile[16 + q * 4 + r][n + l16] = f2b(fmaxf(acc1[r] + bias, 0.f));
            }
        }
    }
    __syncthreads();

    // step 2: p_att = aho @ WattT^T + batt  (depth-2 on W loads)
    {
        int rt = w >> 1, ct = w & 1;
        const u16* bp = WattT + (size_t)(ct * 16 + l16) * 512 + q * 8;
        f32x4 acc = {0,0,0,0};
        s16x8 cb = *(const s16x8*)bp;
        s16x8 nb_ = *(const s16x8*)(bp + 32);
        bp += 64;
        for (int i = 0; i < 14; i++) {
            s16x8 tb = *(const s16x8*)bp; bp += 32;
            s16x8 a = *(const s16x8*)(&tile[rt * 16 + l16][i * 32 + q * 8]);
            acc = MFMA(a, cb, acc);
            cb = nb_; nb_ = tb;
        }
        {
            s16x8 a = *(const s16x8*)(&tile[rt * 16 + l16][14 * 32 + q * 8]);
            acc = MFMA(a, cb, acc);
            a = *(const s16x8*)(&tile[rt * 16 + l16][15 * 32 + q * 8]);
            acc = MFMA(a, nb_, acc);
        }
        int col = ct * 16 + l16;
        if (col < 29) {
            float bias = batt[col];
#pragma unroll
            for (int r = 0; r < 4; r++) {
                int row = c0 + rt * 16 + q * 4 + r;
                outAtt[(size_t)row * 29 + col] = acc[r] + bias;
            }
        }
    }
    __syncthreads();

    // step 3: fref = relu(Pp+Po+Pc+bvis) * aho (in-place); i_ho partials
    {
        int row = t >> 3, g = t & 7;
        int c = c0 + row;
        int rp = c >> 4, bimg = c >> 8;
        int ro = bimg * 16 + (c & 15);
        const u16* ppr = Pp + (size_t)rp * 512;
        const u16* por = Po + (size_t)ro * 512;
        const u16* pcr = Pc + (size_t)bimg * 512;
        float ps = 0.f;
#pragma unroll 4
        for (int j = 0; j < 64; j += 2) {
            int col = g * 64 + j;
            unsigned int upp = *(const unsigned int*)(ppr + col);
            unsigned int upo = *(const unsigned int*)(por + col);
            unsigned int upc = *(const unsigned int*)(pcr + col);
            float2 bv = *(const float2*)(bvis + col);
            unsigned int uah = *(const unsigned int*)(&tile[row][col]);
            float fv0 = fmaxf(b2f((u16)(upp & 0xffff)) + b2f((u16)(upo & 0xffff))
                            + b2f((u16)(upc & 0xffff)) + bv.x, 0.f);
            float fv1 = fmaxf(b2f((u16)(upp >> 16)) + b2f((u16)(upo >> 16))
                            + b2f((u16)(upc >> 16)) + bv.y, 0.f);
            float fr0 = fv0 * b2f((u16)(uah & 0xffff));
            float fr1 = fv1 * b2f((u16)(uah >> 16));
            *(unsigned int*)(&tile[row][col]) = pack2(fr0, fr1);
            ps += fr0 * wipS[col] + fr1 * wipS[col + 1];
        }
        part[row][g] = ps;
    }
    __syncthreads();

    if (t < 32) {
        float s = part[t][0] + part[t][1] + part[t][2] + part[t][3]
                + part[t][4] + part[t][5] + part[t][6] + part[t][7] + bip[0];
        outI[c0 + t] = s;
        adjw[c0 + t] = 1.f / (1.f + expf(-s));
    }

    // step 4: p_ref = fref @ WrefT^T + bref  (depth-2 on W loads)
    {
        int rt = w >> 1, ct = w & 1;
        const u16* bp = WrefT + (size_t)(ct * 16 + l16) * 512 + q * 8;
        f32x4 acc = {0,0,0,0};
        s16x8 cb = *(const s16x8*)bp;
        s16x8 nb_ = *(const s16x8*)(bp + 32);
        bp += 64;
        for (int i = 0; i < 14; i++) {
            s16x8 tb = *(const s16x8*)bp; bp += 32;
            s16x8 a = *(const s16x8*)(&tile[rt * 16 + l16][i * 32 + q * 8]);
            acc = MFMA(a, cb, acc);
            cb = nb_; nb_ = tb;
        }
        {
            s16x8 a = *(const s16x8*)(&tile[rt * 16 + l16][14 * 32 + q * 8]);
            acc = MFMA(a, cb, acc);
            a = *(const s16x8*)(&tile[rt * 16 + l16][15 * 32 + q * 8]);
            acc = MFMA(a, nb_, acc);
        }
        int col = ct * 16 + l16;
        if (col < 29) {
            float bias = bref[col];
#pragma unroll
            for (int r = 0; r < 4; r++) {
                int row = c0 + rt * 16 + q * 4 + r;
                outRef[(size_t)row * 29 + col] = acc[r] + bias;
            }
        }
    }
}

// ---- p_graph: per image, tiny adj contractions + broadcast sum -------------
__global__ __launch_bounds__(256) void pgraph2(
    const float* __restrict__ adjw, const float* __restrict__ Hp,
    const float* __restrict__ HoF, const float* __restrict__ Yh,
    const float* __restrict__ Zo, const float* __restrict__ bg,
    float* __restrict__ outG)
{
    int b = blockIdx.x, t = threadIdx.x;
    __shared__ float adjS[16][16];
    __shared__ float YhS[16][32];
    __shared__ float ZoS[15][32];
    __shared__ float PA[16][32];
    __shared__ float OA[16][32];
    adjS[t >> 4][t & 15] = adjw[b * 256 + t];
    for (int i = t; i < 512; i += 256)
        YhS[i >> 5][i & 31] = Yh[(size_t)(b * 16 + (i >> 5)) * 32 + (i & 31)];
    for (int i = t; i < 480; i += 256)
        ZoS[i >> 5][i & 31] = Zo[(size_t)(b * 15 + (i >> 5)) * 32 + (i & 31)];
    __syncthreads();
    for (int i = t; i < 512; i += 256) {
        int p = i >> 5, j = i & 31;
        float s = 0.f;
#pragma unroll
        for (int o = 0; o < 15; o++) s += adjS[p][o + 1] * ZoS[o][j];
        PA[p][j] = s;
        float s2 = 0.f;
#pragma unroll
        for (int pp = 0; pp < 16; pp++) s2 += adjS[pp][p] * YhS[pp][j];
        OA[p][j] = s2;
    }
    __syncthreads();
    int p = t >> 4, l = t & 15;
    const float* hp = Hp + (size_t)(b * 16 + p) * 32;
    const float* ho = HoF + (size_t)(b * 16 + l) * 32;
    size_t c = (size_t)b * 256 + t;
    for (int j = 0; j < 29; j++) {
        float v = hp[j] + ho[j] + bg[j] + PA[p][j];
        if (l >= 1) v += OA[l][j];
        outG[c * 29 + j] = v;
    }
}

extern "C" void kernel_launch(void* const* d_in, const int* in_sizes, int n_in,
                              void* d_out, int out_size, void* d_ws, size_t ws_size,
                              hipStream_t stream)
{
    const float* people  = (const float*)d_in[0];
    const float* objects = (const float*)d_in[1];
    const float* context = (const float*)d_in[2];
    const float* spatial = (const float*)d_in[3];
    const float* Wvis_w  = (const float*)d_in[4];
    const float* Wvis_b  = (const float*)d_in[5];
    const float* Wspat_w = (const float*)d_in[6];
    const float* Wspat_b = (const float*)d_in[7];
    const float* Wip_w   = (const float*)d_in[8];
    const float* Wip_b   = (const float*)d_in[9];
    const float* Wref_w  = (const float*)d_in[10];
    const float* Wref_b  = (const float*)d_in[11];
    const float* Watt_w  = (const float*)d_in[12];
    const float* Watt_b  = (const float*)d_in[13];
    const float* Woh_w   = (const float*)d_in[14];
    const float* Woh_b   = (const float*)d_in[15];
    const float* Who_w   = (const float*)d_in[16];
    const float* Who_b   = (const float*)d_in[17];
    const float* Wg_w    = (const float*)d_in[18];
    const float* Wg_b    = (const float*)d_in[19];

    char* ws = (char*)d_ws;
    u16* WspatT = (u16*)(ws + OFF_WSPATT);
    u16* WrefT  = (u16*)(ws + OFF_WREFT);
    u16* WattT  = (u16*)(ws + OFF_WATTT);
    u16* WgT    = (u16*)(ws + OFF_WGT);
    u16* Ppb    = (u16*)(ws + OFF_PP);
    u16* Pob    = (u16*)(ws + OFF_PO);
    u16* Pcb    = (u16*)(ws + OFF_PC);
    float* adjw = (float*)(ws + OFF_ADJ);
    float* Hp   = (float*)(ws + OFF_HP);
    float* HoF  = (float*)(ws + OFF_HOF);
    float* Yh   = (float*)(ws + OFF_YH);
    float* Zo   = (float*)(ws + OFF_ZO);

    float* outI   = (float*)d_out;        // i_ho   [16384]
    float* outRef = outI + 16384;         // p_ref  [16384,29]
    float* outAtt = outI + 491520;        // p_att  [16384,29]
    float* outG   = outI + 966656;        // p_graph[16384,29]

    hipMemsetAsync(ws + ZERO_OFF, 0, ZERO_LEN, stream);

    prep_heads<<<64, 256, 0, stream>>>(Wspat_w, Wref_w, Watt_w, Wg_w,
                                       WspatT, WrefT, WattT, WgT);

    fused_gemms<<<904, 256, 0, stream>>>(people, objects, context, Wvis_w,
        Who_w, Who_b, Woh_w, Woh_b, WgT,
        Ppb, Pob, Pcb, Yh, Zo, Hp, HoF);

    mega<<<512, 256, 0, stream>>>(spatial, WspatT, Wspat_b,
                                  Ppb, Pob, Pcb, Wvis_b,
                                  WrefT, Wref_b, WattT, Watt_b,
                                  Wip_w, Wip_b,
                                  outI, outRef, outAtt, adjw);

    pgraph2<<<64, 256, 0, stream>>>(adjw, Hp, HoF, Yh, Zo, Wg_b, outG);
}